// Round 3
// baseline (183.727 us; speedup 1.0000x reference)
//
#include <hip/hip_runtime.h>

#define BATCH 64
#define SEQ   512
#define JDIM  96
#define TN    64
#define KC    64
#define NCH   (SEQ / KC)
#define LDB   72   // bf16 row stride for As/Bs: 144 B, 16B-aligned, breaks pow2 banking

typedef __attribute__((ext_vector_type(8))) short bf16x8;
typedef __attribute__((ext_vector_type(4))) float f32x4;

// exact RNE float->bf16
__device__ __forceinline__ unsigned short f2bf(float f) {
  unsigned u = __float_as_uint(f);
  u += 0x7FFFu + ((u >> 16) & 1u);
  return (unsigned short)(u >> 16);
}

// ---------------- T1: xT[j][b*SEQ+m] = bf16(x[b][m][j])
__global__ __launch_bounds__(256) void transpose_in_kernel(
    const float* __restrict__ x, unsigned short* __restrict__ xT) {
  __shared__ float tile[JDIM * 65];  // [j][rr]
  const int r0 = blockIdx.x * 64;    // 512 blocks cover R = 32768 rows
  const int R = BATCH * SEQ;
  // read: float4 along j (coalesced), scatter to tile rows
  for (int idx = threadIdx.x; idx < 64 * 24; idx += 256) {
    int rr = idx / 24, jg = idx - rr * 24;
    float4 v = *(const float4*)(x + (size_t)(r0 + rr) * JDIM + 4 * jg);
    tile[(4 * jg + 0) * 65 + rr] = v.x;
    tile[(4 * jg + 1) * 65 + rr] = v.y;
    tile[(4 * jg + 2) * 65 + rr] = v.z;
    tile[(4 * jg + 3) * 65 + rr] = v.w;
  }
  __syncthreads();
  // write: 8 bf16 (16B) along rr
  for (int idx = threadIdx.x; idx < JDIM * 8; idx += 256) {
    int jj = idx >> 3, rg = idx & 7;
    const float* t = &tile[jj * 65 + 8 * rg];
    uint4 pk;
    pk.x = (unsigned)f2bf(t[0]) | ((unsigned)f2bf(t[1]) << 16);
    pk.y = (unsigned)f2bf(t[2]) | ((unsigned)f2bf(t[3]) << 16);
    pk.z = (unsigned)f2bf(t[4]) | ((unsigned)f2bf(t[5]) << 16);
    pk.w = (unsigned)f2bf(t[6]) | ((unsigned)f2bf(t[7]) << 16);
    *(uint4*)(&xT[(size_t)jj * R + r0 + 8 * rg]) = pk;
  }
}

// ---------------- Fused: per block (j, n-tile 64): C[64b x 64n] = X_j * exp(pre+off)^T via MFMA, /L
// K-loop software pipeline: global loads for chunk ch+1 issued into registers
// right after barrier 1, overlapping MFMA + barrier 2 + next exp/pack.
__global__ __launch_bounds__(256, 3) void fused_kernel(
    const unsigned short* __restrict__ xT,  // [J][B*SEQ] bf16
    const float* __restrict__ off,          // [J][SEQ][SEQ]
    const float* __restrict__ pre,          // [SEQ][SEQ]
    float* __restrict__ outT) {             // [J][SEQ][B]
  __shared__ unsigned short As[BATCH * LDB];  // [b][k] k-contiguous
  __shared__ unsigned short Bs[TN * LDB];     // [n][k] k-contiguous
  __shared__ float Lred[TN * 17];
  __shared__ float Linv[TN];

  const int j  = blockIdx.x % JDIM;
  const int n0 = (blockIdx.x / JDIM) * TN;

  const int tid  = threadIdx.x;
  const int lane = tid & 63;
  const int wid  = tid >> 6;      // 4 waves
  const int ln   = lane & 15;
  const int quad = lane >> 4;
  const int bw   = (wid & 1) * 32;
  const int nw   = (wid >> 1) * 32;

  f32x4 acc[2][2];
#pragma unroll
  for (int i = 0; i < 2; ++i)
#pragma unroll
    for (int q = 0; q < 2; ++q) acc[i][q] = (f32x4){0.f, 0.f, 0.f, 0.f};
  float Lpart[4] = {0.f, 0.f, 0.f, 0.f};

  const unsigned short* xTj = xT + (size_t)j * (BATCH * SEQ);
  const float* offj = off + (size_t)j * (SEQ * SEQ);

  const int a_kg = tid & 7;    // 8 groups x 8 bf16 per KC row
  const int a_b  = tid >> 3;   // 0..31 (+32)
  const int b_mg = tid & 15;
  const int b_n  = tid >> 4;   // 0..15 (4 passes)

  const unsigned short* pA = xTj + (size_t)a_b * SEQ + 8 * a_kg;
  const float* pO = offj + (size_t)(n0 + b_n) * SEQ + 4 * b_mg;
  const float* pP = pre  + (size_t)(n0 + b_n) * SEQ + 4 * b_mg;

  uint4  rA[2];
  float4 rO[4], rP[4];

  // prefetch chunk 0
  rA[0] = *(const uint4*)(pA);
  rA[1] = *(const uint4*)(pA + 32 * SEQ);
#pragma unroll
  for (int p = 0; p < 4; ++p) {
    rO[p] = *(const float4*)(pO + (size_t)(16 * p) * SEQ);
    rP[p] = *(const float4*)(pP + (size_t)(16 * p) * SEQ);
  }

  for (int ch = 0; ch < NCH; ++ch) {
    // ---- consume prefetch: A to LDS, exp+pack B to LDS
    *(uint4*)(&As[a_b * LDB + 8 * a_kg]) = rA[0];
    *(uint4*)(&As[(a_b + 32) * LDB + 8 * a_kg]) = rA[1];
#pragma unroll
    for (int p = 0; p < 4; ++p) {
      const float e0 = __expf(rO[p].x + rP[p].x);
      const float e1 = __expf(rO[p].y + rP[p].y);
      const float e2 = __expf(rO[p].z + rP[p].z);
      const float e3 = __expf(rO[p].w + rP[p].w);
      Lpart[p] += (e0 + e1) + (e2 + e3);
      uint2 pk;
      pk.x = (unsigned)f2bf(e0) | ((unsigned)f2bf(e1) << 16);
      pk.y = (unsigned)f2bf(e2) | ((unsigned)f2bf(e3) << 16);
      *(uint2*)(&Bs[(b_n + 16 * p) * LDB + 4 * b_mg]) = pk;
    }
    __syncthreads();

    // ---- issue next chunk's global loads (latency overlaps MFMA + barrier + next exp)
    if (ch + 1 < NCH) {
      const int m1 = (ch + 1) * KC;
      rA[0] = *(const uint4*)(pA + m1);
      rA[1] = *(const uint4*)(pA + 32 * SEQ + m1);
#pragma unroll
      for (int p = 0; p < 4; ++p) {
        rO[p] = *(const float4*)(pO + (size_t)(16 * p) * SEQ + m1);
        rP[p] = *(const float4*)(pP + (size_t)(16 * p) * SEQ + m1);
      }
    }

    // ---- MFMA: wave computes 32x32 quadrant as 2x2 frags of 16x16x32
#pragma unroll
    for (int ks = 0; ks < KC; ks += 32) {
      bf16x8 afrag[2], bfrag[2];
#pragma unroll
      for (int i = 0; i < 2; ++i)
        afrag[i] = *(const bf16x8*)(&As[(bw + 16 * i + ln) * LDB + ks + 8 * quad]);
#pragma unroll
      for (int q = 0; q < 2; ++q)
        bfrag[q] = *(const bf16x8*)(&Bs[(nw + 16 * q + ln) * LDB + ks + 8 * quad]);
#pragma unroll
      for (int i = 0; i < 2; ++i)
#pragma unroll
        for (int q = 0; q < 2; ++q)
          acc[i][q] = __builtin_amdgcn_mfma_f32_16x16x32_bf16(afrag[i], bfrag[q], acc[i][q], 0, 0, 0);
    }
    __syncthreads();
  }

  // ---- reduce L across the 16 m-group partials per row
#pragma unroll
  for (int p = 0; p < 4; ++p) Lred[(b_n + 16 * p) * 17 + b_mg] = Lpart[p];
  __syncthreads();
  if (tid < TN) {
    float s = 0.f;
#pragma unroll
    for (int i = 0; i < 16; ++i) s += Lred[tid * 17 + i];
    Linv[tid] = 1.0f / s;
  }
  __syncthreads();

  // ---- epilogue: C/D layout col(=n)=lane&15, row(=b)=quad*4+reg -> float4 along b
  float* outTj = outT + (size_t)j * (SEQ * BATCH);
#pragma unroll
  for (int q = 0; q < 2; ++q) {
    const int nc = nw + 16 * q + ln;
    const float linv = Linv[nc];
#pragma unroll
    for (int i = 0; i < 2; ++i) {
      float4 v;
      v.x = acc[i][q][0] * linv;
      v.y = acc[i][q][1] * linv;
      v.z = acc[i][q][2] * linv;
      v.w = acc[i][q][3] * linv;
      *(float4*)(&outTj[(size_t)(n0 + nc) * BATCH + bw + 16 * i + 4 * quad]) = v;
    }
  }
}

// ---------------- T2: out[b][n][j] = outT[j][n][b]
__global__ __launch_bounds__(256) void transpose_out_kernel(
    const float* __restrict__ outT, float* __restrict__ out) {
  __shared__ float tile[JDIM * 65];  // [j][b]
  const int n = blockIdx.x;          // 512 blocks
  for (int idx = threadIdx.x; idx < JDIM * 16; idx += 256) {
    int jj = idx >> 4, g = idx & 15;   // float4 along b, coalesced
    float4 v = *(const float4*)(outT + ((size_t)jj * SEQ + n) * BATCH + 4 * g);
    float* t = &tile[jj * 65 + 4 * g];
    t[0] = v.x; t[1] = v.y; t[2] = v.z; t[3] = v.w;
  }
  __syncthreads();
  for (int idx = threadIdx.x; idx < BATCH * 24; idx += 256) {
    int b = idx / 24, jg = idx - b * 24;  // float4 along j, coalesced
    float4 w;
    w.x = tile[(4 * jg + 0) * 65 + b];
    w.y = tile[(4 * jg + 1) * 65 + b];
    w.z = tile[(4 * jg + 2) * 65 + b];
    w.w = tile[(4 * jg + 3) * 65 + b];
    *(float4*)(out + ((size_t)b * SEQ + n) * JDIM + 4 * jg) = w;
  }
}

extern "C" void kernel_launch(void* const* d_in, const int* in_sizes, int n_in,
                              void* d_out, int out_size, void* d_ws, size_t ws_size,
                              hipStream_t stream) {
  const float* x   = (const float*)d_in[0];  // [64, 512, 96]
  const float* off = (const float*)d_in[1];  // [96, 512, 512]
  const float* pre = (const float*)d_in[2];  // [512, 512]
  float* out = (float*)d_out;                // [64, 512, 96]

  unsigned short* xT = (unsigned short*)d_ws;                 // bf16 [96][64*512] = 6.29 MB
  float* outT = (float*)((char*)d_ws + (size_t)JDIM * BATCH * SEQ * sizeof(unsigned short));
                                                              // f32 [96][512][64] = 12.58 MB

  transpose_in_kernel<<<BATCH * SEQ / 64, 256, 0, stream>>>(x, xT);
  fused_kernel<<<JDIM * (SEQ / TN), 256, 0, stream>>>(xT, off, pre, outT);
  transpose_out_kernel<<<SEQ, 256, 0, stream>>>(outT, out);
}